// Round 1
// 109.113 us; speedup vs baseline: 1.0310x; 1.0310x over previous
//
#include <hip/hip_runtime.h>
#include <stdint.h>

// ---------------------------------------------------------------------------
// VQ-VAE VectorQuantizer forward (MI355X):
//   out  = encoderout (faithful source bug)
//   loss_sum = sum_all x^2 + sum_m min_n (||e_n||^2 - 2 x_m.e_n)
//   cbl = loss_sum/ELEMS ; comm = cbl ; loss = 1.25*cbl
// enc [32,256,32,32] f32 NCHW, codebook [1024,256] f32.
// R2: 2 dispatches (prep zeroes accum/done; main finishes via atomic ticket).
//     256 blocks x 128 rows (mi=4): halves LDS B-read traffic per MFMA and
//     halves codebook L2 traffic. Double-buffered B staging (Bs + reused As),
//     chunk-0 prefetch before phase A, ONE barrier per K-chunk.
// ---------------------------------------------------------------------------

#define EMB 256
#define ELEMS 8388608   // 32*256*32*32
#define NBLK 256

typedef __bf16 bf16x8 __attribute__((ext_vector_type(8)));
typedef float  f32x4  __attribute__((ext_vector_type(4)));

union Frag { uint4 u4; bf16x8 v; };

__device__ __forceinline__ unsigned short f2bf(float f) {
    unsigned u = __float_as_uint(f);
    u += 0x7FFFu + ((u >> 16) & 1u);   // RNE
    return (unsigned short)(u >> 16);
}

// ---------------------------------------------------------------------------
// prep (R1-proven): codebook f32 [1024][256] -> swizzled bf16 global; chunk
// (n, kc=k/8) at byte n*512 + ((kc ^ (n&7))*16). esq[n] = ||e_n||^2.
// Also zeroes accum + done (replaces the memset dispatch).
// ---------------------------------------------------------------------------
__global__ __launch_bounds__(256) void vq_prep(const float* __restrict__ cb,
                                               uint2* __restrict__ cbswz,
                                               float* __restrict__ esq,
                                               float* __restrict__ accum,
                                               unsigned* __restrict__ done) {
    if (blockIdx.x == 0 && threadIdx.x == 0) { accum[0] = 0.f; done[0] = 0u; }

    const int tid  = threadIdx.x;
    const int w    = tid >> 6;
    const int lane = tid & 63;
    const int n    = blockIdx.x * 4 + w;

    const float4* row = (const float4*)(cb + n * EMB);
    float4 v = row[lane];                       // k = 4*lane .. 4*lane+3

    float s = v.x * v.x + v.y * v.y + v.z * v.z + v.w * v.w;
    #pragma unroll
    for (int m = 1; m <= 32; m <<= 1) s += __shfl_xor(s, m);
    if (lane == 0) esq[n] = s;

    unsigned lo = (unsigned)f2bf(v.x) | ((unsigned)f2bf(v.y) << 16);
    unsigned hi = (unsigned)f2bf(v.z) | ((unsigned)f2bf(v.w) << 16);
    int kc = lane >> 1;          // 16B chunk index (8 bf16)
    int h  = lane & 1;
    cbswz[n * 64 + ((kc ^ (n & 7)) << 1) + h] = make_uint2(lo, hi);
}

// ---------------------------------------------------------------------------
// main: block = 128 hw-rows of one batch image; grid 256 (1 block/CU).
// 8 waves: wm = w>>2 (2 groups x 64 rows), wn = w&3 (4 n-subgroups).
// Phase A: chunk-0 B prefetch issued first, then coalesced float4 copy
// enc->out, fused sum(x^2), bf16 transpose into swizzled LDS (As, 64 KB).
// A-frags (4 per wave) live in registers for the whole K-loop; As is then
// reused as the second B staging buffer. One barrier per 64-code chunk;
// next chunk's global_load_lds issued before computing the current one.
// ---------------------------------------------------------------------------

#define STAGE(nc_, dst_) do {                                                  \
    const char* _src = cbbase + (size_t)(nc_) * 32768;                         \
    _Pragma("unroll")                                                          \
    for (int _i = 0; _i < 4; ++_i) {                                           \
        const int _o = (_i * 8 + w) * 1024;    /* wave-uniform LDS base */     \
        __builtin_amdgcn_global_load_lds(                                      \
            (const __attribute__((address_space(1))) unsigned int*)            \
                (_src + _o + lane * 16),                                       \
            (__attribute__((address_space(3))) unsigned int*)                  \
                ((char*)(dst_) + _o),                                          \
            16, 0, 0);                                                         \
    } } while (0)

#define CHUNK(nc_, buf_) do {                                                  \
    f32x4 _a0 = (f32x4){0.f,0.f,0.f,0.f};                                      \
    f32x4 _a1 = (f32x4){0.f,0.f,0.f,0.f};                                      \
    f32x4 _a2 = (f32x4){0.f,0.f,0.f,0.f};                                      \
    f32x4 _a3 = (f32x4){0.f,0.f,0.f,0.f};                                      \
    _Pragma("unroll")                                                          \
    for (int _ks = 0; _ks < 8; ++_ks) {                                        \
        Frag _fb; _fb.u4 = (buf_)[nl * 32 + ((_ks * 4 + q) ^ (nl & 7))];       \
        _a0 = __builtin_amdgcn_mfma_f32_16x16x32_bf16(afr[0][_ks], _fb.v, _a0, 0, 0, 0); \
        _a1 = __builtin_amdgcn_mfma_f32_16x16x32_bf16(afr[1][_ks], _fb.v, _a1, 0, 0, 0); \
        _a2 = __builtin_amdgcn_mfma_f32_16x16x32_bf16(afr[2][_ks], _fb.v, _a2, 0, 0, 0); \
        _a3 = __builtin_amdgcn_mfma_f32_16x16x32_bf16(afr[3][_ks], _fb.v, _a3, 0, 0, 0); \
    }                                                                          \
    const float _eq = esq[(nc_) * 64 + nl];                                    \
    _Pragma("unroll")                                                          \
    for (int _r2 = 0; _r2 < 4; ++_r2) {                                        \
        rmin[0][_r2] = fminf(rmin[0][_r2], fmaf(-2.f, _a0[_r2], _eq));         \
        rmin[1][_r2] = fminf(rmin[1][_r2], fmaf(-2.f, _a1[_r2], _eq));         \
        rmin[2][_r2] = fminf(rmin[2][_r2], fmaf(-2.f, _a2[_r2], _eq));         \
        rmin[3][_r2] = fminf(rmin[3][_r2], fmaf(-2.f, _a3[_r2], _eq));         \
    } } while (0)

__global__ __launch_bounds__(512, 2) void vq_main(const float* __restrict__ enc,
                                                  const uint4* __restrict__ cbswz,
                                                  const float* __restrict__ esq,
                                                  float* __restrict__ out,
                                                  float* __restrict__ accum,
                                                  unsigned* __restrict__ done) {
    __shared__ uint4 As[4096];          // 64 KB: 128 rows x 512B (swizzled bf16); reused as B buf 1
    __shared__ uint4 Bs[2048];          // 32 KB: 64 codes x 512B (swizzled bf16); B buf 0
    __shared__ float dmin[4][128];
    __shared__ float partsA[8];
    __shared__ float partsB[2];

    const int tid  = threadIdx.x;
    const int w    = tid >> 6;
    const int lane = tid & 63;
    const int q    = lane >> 4;         // quad 0..3
    const int c    = lane & 15;
    const int wm   = w >> 2;            // 0..1 (64-row groups)
    const int wn   = w & 3;             // 0..3 (16-code subgroups)

    const int b   = blockIdx.x >> 3;            // image
    const int hw0 = (blockIdx.x & 7) << 7;      // 128-row slab
    const float* encB = enc + (size_t)b * 262144 + hw0;
    float*       outB = out + (size_t)b * 262144 + hw0;
    const char* cbbase = (const char*)cbswz;

    // ---- prefetch B chunk 0 into Bs; latency hides under phase A ----
    STAGE(0, Bs);

    // ---- phase A: coalesced copy + sum(x^2) + bf16 transpose into LDS ----
    const int q4 = tid & 15;            // hw quad (4 hw rows)
    const int kg = tid >> 4;            // 0..31 -> k0 = kg*8
    float sx = 0.f;
    #pragma unroll
    for (int h2 = 0; h2 < 2; ++h2) {    // two 64-row halves
        union { float4 f4; float f[4]; } v[8];
        #pragma unroll
        for (int j = 0; j < 8; ++j)
            v[j].f4 = *(const float4*)(encB + (size_t)(kg * 8 + j) * 1024 + h2 * 64 + q4 * 4);
        #pragma unroll
        for (int j = 0; j < 8; ++j) {
            *(float4*)(outB + (size_t)(kg * 8 + j) * 1024 + h2 * 64 + q4 * 4) = v[j].f4;
            sx = fmaf(v[j].f[0], v[j].f[0], sx);
            sx = fmaf(v[j].f[1], v[j].f[1], sx);
            sx = fmaf(v[j].f[2], v[j].f[2], sx);
            sx = fmaf(v[j].f[3], v[j].f[3], sx);
        }
        #pragma unroll
        for (int i = 0; i < 4; ++i) {
            unsigned short us[8];
            #pragma unroll
            for (int j = 0; j < 8; ++j) us[j] = f2bf(v[j].f[i]);
            uint4 pk;
            pk.x = (unsigned)us[0] | ((unsigned)us[1] << 16);
            pk.y = (unsigned)us[2] | ((unsigned)us[3] << 16);
            pk.z = (unsigned)us[4] | ((unsigned)us[5] << 16);
            pk.w = (unsigned)us[6] | ((unsigned)us[7] << 16);
            const int r = h2 * 64 + q4 * 4 + i;
            As[r * 32 + (kg ^ (r & 7))] = pk;
        }
    }
    #pragma unroll
    for (int m = 1; m <= 32; m <<= 1) sx += __shfl_xor(sx, m);
    if (lane == 0) partsA[w] = sx;
    __syncthreads();                    // As ready (also drains chunk-0 DMA)

    // ---- A fragments: wave's 64 rows x full K into registers ----
    bf16x8 afr[4][8];
    #pragma unroll
    for (int mi = 0; mi < 4; ++mi) {
        const int r = wm * 64 + mi * 16 + c;
        #pragma unroll
        for (int ks = 0; ks < 8; ++ks) {
            Frag fa; fa.u4 = As[r * 32 + ((ks * 4 + q) ^ (r & 7))];
            afr[mi][ks] = fa.v;
        }
    }

    float rmin[4][4];
    #pragma unroll
    for (int mi = 0; mi < 4; ++mi)
        #pragma unroll
        for (int r2 = 0; r2 < 4; ++r2) rmin[mi][r2] = 1e30f;

    const int nl = wn * 16 + c;

    __syncthreads();                    // all A-frag reads done -> As reusable

    // ---- K-loop: 16 chunks of 64 codes; 1 barrier/chunk, dbuf Bs/As ----
    for (int i = 0; i < 8; ++i) {
        if (i) __syncthreads();         // chunk 2i staged + As consumed
        STAGE(2 * i + 1, As);           // next chunk in flight during compute
        CHUNK(2 * i, Bs);
        __syncthreads();                // chunk 2i+1 staged + Bs consumed
        if (i < 7) STAGE(2 * i + 2, Bs);
        CHUNK(2 * i + 1, (const uint4*)As);
    }

    // min across the 16 code-columns (xor over c bits), then per-row mins
    #pragma unroll
    for (int mi = 0; mi < 4; ++mi)
        #pragma unroll
        for (int r2 = 0; r2 < 4; ++r2) {
            float x = rmin[mi][r2];
            x = fminf(x, __shfl_xor(x, 1));
            x = fminf(x, __shfl_xor(x, 2));
            x = fminf(x, __shfl_xor(x, 4));
            x = fminf(x, __shfl_xor(x, 8));
            rmin[mi][r2] = x;
        }
    if (c == 0) {
        #pragma unroll
        for (int mi = 0; mi < 4; ++mi)
            #pragma unroll
            for (int r2 = 0; r2 < 4; ++r2)
                dmin[wn][wm * 64 + mi * 16 + q * 4 + r2] = rmin[mi][r2];
    }
    __syncthreads();

    if (tid < 128) {
        float vr = fminf(fminf(dmin[0][tid], dmin[1][tid]),
                         fminf(dmin[2][tid], dmin[3][tid]));
        #pragma unroll
        for (int m = 1; m <= 32; m <<= 1) vr += __shfl_xor(vr, m);
        if ((tid & 63) == 0) partsB[tid >> 6] = vr;
    }
    __syncthreads();

    if (tid == 0) {
        float s = partsB[0] + partsB[1];
        #pragma unroll
        for (int w2 = 0; w2 < 8; ++w2) s += partsA[w2];
        atomicAdd(accum, s);
        __threadfence();                          // release our add
        unsigned prev = atomicAdd(done, 1u);      // device-scope ticket
        if (prev == NBLK - 1) {
            float tot = atomicAdd(accum, 0.0f);   // coherent read of total
            float cbl = tot * (1.0f / (float)ELEMS);
            out[ELEMS + 0] = 1.25f * cbl;   // loss = cbl + BETA*cbl
            out[ELEMS + 1] = cbl;           // codebook_loss
            out[ELEMS + 2] = cbl;           // commitment_loss
        }
    }
}

extern "C" void kernel_launch(void* const* d_in, const int* in_sizes, int n_in,
                              void* d_out, int out_size, void* d_ws, size_t ws_size,
                              hipStream_t stream) {
    const float* enc = (const float*)d_in[0];
    const float* cb  = (const float*)d_in[1];
    float* out = (float*)d_out;

    float*    accum = (float*)d_ws;                    // 4 B
    unsigned* done  = (unsigned*)((char*)d_ws + 64);   // 4 B
    float*    esq   = (float*)((char*)d_ws + 256);     // 4 KB
    uint2*    cbswz = (uint2*)((char*)d_ws + 8192);    // 512 KB

    vq_prep<<<dim3(256), dim3(256), 0, stream>>>(cb, cbswz, esq, accum, done);
    vq_main<<<dim3(NBLK), dim3(512), 0, stream>>>(enc, (const uint4*)cbswz, esq,
                                                  out, accum, done);
}